// Round 6
// baseline (752.138 us; speedup 1.0000x reference)
//
#include <hip/hip_runtime.h>

#define H 128

typedef __bf16 bf8_t __attribute__((ext_vector_type(8)));
typedef float  f4_t  __attribute__((ext_vector_type(4)));

#define MFMA16(a, b, c) __builtin_amdgcn_mfma_f32_16x16x32_bf16((a), (b), (c), 0, 0, 0)

__device__ __forceinline__ float silu_f(float v) {
    return v * (1.0f / (1.0f + __expf(-v)));
}

// LDS-only barrier: does NOT drain vmcnt, so global prefetch stays in flight.
__device__ __forceinline__ void bar_lds() {
    asm volatile("s_waitcnt lgkmcnt(0)\ns_barrier" ::: "memory");
}

__device__ __forceinline__ float wload(const void* p, int idx, bool f32) {
    return f32 ? ((const float*)p)[idx] : (float)((const __bf16*)p)[idx];
}

__device__ __forceinline__ bf8_t hload8(const void* p, size_t off, bool f32) {
    bf8_t v;
    if (f32) {
        const float4* q = (const float4*)((const float*)p + off);
        const float4 a = q[0], b = q[1];
        v[0]=(__bf16)a.x; v[1]=(__bf16)a.y; v[2]=(__bf16)a.z; v[3]=(__bf16)a.w;
        v[4]=(__bf16)b.x; v[5]=(__bf16)b.y; v[6]=(__bf16)b.z; v[7]=(__bf16)b.w;
    } else {
        v = *(const bf8_t*)((const __bf16*)p + off);
    }
    return v;
}

__device__ __forceinline__ int eidx(const void* ei, int i, bool i64) {
    return i64 ? (int)((const long long*)ei)[i] : ((const int*)ei)[i];
}

// ---------------------------------------------------------------------------
// dtype detection
// ---------------------------------------------------------------------------
__global__ void detect_kernel(const unsigned short* __restrict__ hraw,
                              const int* __restrict__ eiraw, int* __restrict__ flags)
{
    __shared__ int s_nf, s_oddnz;
    if (threadIdx.x == 0) { s_nf = 0; s_oddnz = 0; }
    __syncthreads();
    int nf = 0;
    for (int i = threadIdx.x; i < 16384; i += blockDim.x) {
        const unsigned short u = hraw[i];
        if (((u >> 7) & 0xFF) == 0xFF) nf++;
    }
    int onz = 0;
    for (int i = threadIdx.x; i < 512; i += blockDim.x) {
        if (eiraw[2*i + 1] != 0) onz++;
    }
    if (nf)  atomicAdd(&s_nf, nf);
    if (onz) atomicAdd(&s_oddnz, onz);
    __syncthreads();
    if (threadIdx.x == 0) {
        flags[0] = (s_nf > 0) ? 1 : 0;
        flags[1] = (s_oddnz == 0) ? 1 : 0;
    }
}

// ---------------------------------------------------------------------------
// CSR build: dst histogram (raw ei) -> scan -> scatter+geometry (fused)
// ---------------------------------------------------------------------------
__global__ void histd_kernel(const void* __restrict__ ei, int* __restrict__ cnt,
                             const int* __restrict__ flags, int Ee)
{
    const int e = blockIdx.x*blockDim.x + threadIdx.x;
    if (e < Ee) atomicAdd(&cnt[eidx(ei, Ee + e, flags[1] != 0)], 1);
}

__global__ void scanA_kernel(const int* __restrict__ cnt, int* __restrict__ bsum, int Nn)
{
    __shared__ int s[512];
    const int gi = blockIdx.x*512 + threadIdx.x;
    s[threadIdx.x] = (gi < Nn) ? cnt[gi] : 0;
    __syncthreads();
    for (int off = 256; off > 0; off >>= 1) {
        if (threadIdx.x < off) s[threadIdx.x] += s[threadIdx.x + off];
        __syncthreads();
    }
    if (threadIdx.x == 0) bsum[blockIdx.x] = s[0];
}

__global__ void scanB_kernel(int* __restrict__ bsum, int* __restrict__ base, int nCh)
{
    if (threadIdx.x == 0) {
        int acc = 0;
        for (int b = 0; b < nCh; ++b) { base[b] = acc; acc += bsum[b]; }
    }
}

__global__ void scanC_kernel(const int* __restrict__ cnt, const int* __restrict__ base,
                             int* __restrict__ off, int* __restrict__ cursor, int Nn)
{
    __shared__ int s[512];
    const int i  = threadIdx.x;
    const int gi = blockIdx.x*512 + i;
    const int v  = (gi < Nn) ? cnt[gi] : 0;
    s[i] = v;
    __syncthreads();
    for (int o = 1; o < 512; o <<= 1) {
        const int t = (i >= o) ? s[i - o] : 0;
        __syncthreads();
        s[i] += t;
        __syncthreads();
    }
    const int excl = s[i] - v;
    if (gi <= Nn) {
        const int val = base[blockIdx.x] + excl;
        off[gi] = val;
        if (gi < Nn) cursor[gi] = val;
    }
}

// scatter + geometry: compute sorted slot, write srcs/dsts/d2/rel4 at slot
__global__ void scatgeo_kernel(const void* __restrict__ ei, int* __restrict__ cursor,
                               int* __restrict__ srcs, int* __restrict__ dsts,
                               float* __restrict__ d2buf, float4* __restrict__ rel4,
                               const void* __restrict__ x,
                               const int* __restrict__ flags, int Ee)
{
    const int e = blockIdx.x*blockDim.x + threadIdx.x;
    if (e >= Ee) return;
    const bool i64 = flags[1] != 0;
    const bool f32 = flags[0] != 0;
    const int s = eidx(ei, e, i64);
    const int d = eidx(ei, Ee + e, i64);
    const int p = atomicAdd(&cursor[d], 1);
    srcs[p] = s;
    dsts[p] = d;
    float r[3];
    #pragma unroll
    for (int c = 0; c < 3; ++c)
        r[c] = wload(x, s*3 + c, f32) - wload(x, d*3 + c, f32);
    const float d2 = r[0]*r[0] + r[1]*r[1] + r[2]*r[2];
    d2buf[p] = d2;
    float4 o; o.x = r[0]; o.y = r[1]; o.z = r[2]; o.w = d2;
    rel4[p] = o;
}

// ---------------------------------------------------------------------------
// Projection kernel: PB[n][0:128]   = (h @ We1[0:128])[n]
//                    PB[n][128:256] = (h @ We1[128:256])[n] + be1
// ---------------------------------------------------------------------------
__global__ __launch_bounds__(512, 2)
void proj_kernel(const void* __restrict__ h, const void* __restrict__ We1,
                 const void* __restrict__ be1, const int* __restrict__ flags,
                 __bf16* __restrict__ PB, int Nn)
{
    const bool f32 = flags[0] != 0;
    const int tid  = threadIdx.x;
    const int wv   = tid >> 6;
    const int lane = tid & 63;
    const int quad = lane >> 4;
    const int l15  = lane & 15;

    bf8_t bW[4][2];
    float bias[2];
    #pragma unroll
    for (int t = 0; t < 2; ++t) {
        const int n    = wv*32 + t*16 + l15;
        const int rb   = (n < 128) ? 0 : 128;
        const int col  = n & 127;
        #pragma unroll
        for (int kc = 0; kc < 4; ++kc) {
            bf8_t v;
            #pragma unroll
            for (int j = 0; j < 8; ++j)
                v[j] = (__bf16)wload(We1, (rb + kc*32 + quad*8 + j)*H + col, f32);
            bW[kc][t] = v;
        }
        bias[t] = (n < 128) ? 0.f : wload(be1, col, f32);
    }

    __shared__ __bf16 s_h[32*136];

    const int tiles = (Nn + 31) >> 5;
    for (int tile = blockIdx.x; tile < tiles; tile += gridDim.x) {
        const int nb = tile << 5;
        __syncthreads();
        {
            const int m = tid >> 4, c = tid & 15;
            int node = nb + m; if (node >= Nn) node = Nn - 1;
            *(bf8_t*)&s_h[m*136 + c*8] = hload8(h, (size_t)node*H + c*8, f32);
        }
        __syncthreads();

        f4_t acc[2][2];
        #pragma unroll
        for (int mm = 0; mm < 2; ++mm)
            #pragma unroll
            for (int t = 0; t < 2; ++t) acc[mm][t] = (f4_t){0.f,0.f,0.f,0.f};
        #pragma unroll
        for (int kc = 0; kc < 4; ++kc) {
            #pragma unroll
            for (int mm = 0; mm < 2; ++mm) {
                const bf8_t a = *(const bf8_t*)&s_h[(mm*16 + l15)*136 + quad*8 + kc*32];
                acc[mm][0] = MFMA16(a, bW[kc][0], acc[mm][0]);
                acc[mm][1] = MFMA16(a, bW[kc][1], acc[mm][1]);
            }
        }
        #pragma unroll
        for (int mm = 0; mm < 2; ++mm)
            #pragma unroll
            for (int i = 0; i < 4; ++i) {
                const int row = nb + mm*16 + quad*4 + i;
                if (row < Nn) {
                    #pragma unroll
                    for (int t = 0; t < 2; ++t)
                        PB[(size_t)row*256 + wv*32 + t*16 + l15] =
                            (__bf16)(acc[mm][t][i] + bias[t]);
                }
            }
    }
}

// ---------------------------------------------------------------------------
// Edge kernel: 64-edge dst-sorted tiles, 3 lgkm-only barriers per tile.
// Layer 1 = gather PB rows + add + d2*w1d + silu. Layers 2/3 = MFMA with
// register-resident weights. 2-deep prefetch pipeline.
// ---------------------------------------------------------------------------
__global__ __launch_bounds__(512, 2)
void egnn_edge_pipe_kernel(const __bf16* __restrict__ PB,
                           const int* __restrict__ srcs, const int* __restrict__ dsts,
                           const float* __restrict__ d2buf,
                           const void* __restrict__ We1,  // row 256 only (w1d)
                           const void* __restrict__ We2, const void* __restrict__ be2,
                           const void* __restrict__ Wc1, const void* __restrict__ bc1,
                           const void* __restrict__ Wc2, const int* __restrict__ flags,
                           __bf16* __restrict__ m_buf, float* __restrict__ cw_buf,
                           int Ee)
{
    const bool f32 = flags[0] != 0;
    const int tid  = threadIdx.x;
    const int wv   = tid >> 6;
    const int lane = tid & 63;
    const int quad = lane >> 4;
    const int l15  = lane & 15;
    const int mg   = wv >> 2;
    const int ng   = wv & 3;

    bf8_t bW2[4][2], bWc[4][2];
    float be2v[2], bc1v[2], wc2v[2];
    #pragma unroll
    for (int t = 0; t < 2; ++t) {
        const int n = ng*32 + t*16 + l15;
        #pragma unroll
        for (int kc = 0; kc < 4; ++kc) {
            bf8_t v, u;
            #pragma unroll
            for (int j = 0; j < 8; ++j) {
                v[j] = (__bf16)wload(We2, (kc*32 + quad*8 + j)*H + n, f32);
                u[j] = (__bf16)wload(Wc1, (kc*32 + quad*8 + j)*H + n, f32);
            }
            bW2[kc][t] = v;
            bWc[kc][t] = u;
        }
        be2v[t] = wload(be2, n, f32);
        bc1v[t] = wload(bc1, n, f32);
        wc2v[t] = wload(Wc2, n, f32);
    }

    const int em = tid >> 3;
    const int ch = tid & 7;
    float w1dA[8], w1dB[8];
    #pragma unroll
    for (int j = 0; j < 8; ++j) {
        w1dA[j] = wload(We1, 256*H + ch*8 + j, f32);
        w1dB[j] = wload(We1, 256*H + (ch+8)*8 + j, f32);
    }

    __shared__ __bf16 s_m1[64*136];
    __shared__ __bf16 s_m2[64*136];
    __shared__ float  s_cw[64*4];

    const int tiles = (Ee + 63) >> 6;

    bf8_t rA0, rA1, rB0, rB1;
    float d2cur;
    int   s_n, d_n;
    float d2nxt;
    {
        int e0 = blockIdx.x*64 + em; if (e0 >= Ee) e0 = Ee - 1;
        const int sc = srcs[e0], dc = dsts[e0];
        d2cur = d2buf[e0];
        rA0 = *(const bf8_t*)(PB + (size_t)sc*256 + ch*8);
        rA1 = *(const bf8_t*)(PB + (size_t)sc*256 + (ch+8)*8);
        rB0 = *(const bf8_t*)(PB + (size_t)dc*256 + 128 + ch*8);
        rB1 = *(const bf8_t*)(PB + (size_t)dc*256 + 128 + (ch+8)*8);
        const int t1 = blockIdx.x + gridDim.x;
        const int tt = (t1 < tiles) ? t1 : blockIdx.x;
        int e1 = tt*64 + em; if (e1 >= Ee) e1 = Ee - 1;
        s_n = srcs[e1]; d_n = dsts[e1]; d2nxt = d2buf[e1];
    }

    for (int t = blockIdx.x; t < tiles; t += gridDim.x) {
        {
            bf8_t o0, o1;
            #pragma unroll
            for (int j = 0; j < 8; ++j) {
                const float f0 = (float)rA0[j] + (float)rB0[j] + d2cur*w1dA[j];
                const float f1 = (float)rA1[j] + (float)rB1[j] + d2cur*w1dB[j];
                o0[j] = (__bf16)silu_f(f0);
                o1[j] = (__bf16)silu_f(f1);
            }
            *(bf8_t*)&s_m1[em*136 + ch*8]       = o0;
            *(bf8_t*)&s_m1[em*136 + (ch+8)*8]   = o1;
        }
        {
            const int sc = s_n, dc = d_n;
            rA0 = *(const bf8_t*)(PB + (size_t)sc*256 + ch*8);
            rA1 = *(const bf8_t*)(PB + (size_t)sc*256 + (ch+8)*8);
            rB0 = *(const bf8_t*)(PB + (size_t)dc*256 + 128 + ch*8);
            rB1 = *(const bf8_t*)(PB + (size_t)dc*256 + 128 + (ch+8)*8);
            d2cur = d2nxt;
            const int t2 = t + 2*gridDim.x;
            const int tt = (t2 < tiles) ? t2 : t;
            int e2 = tt*64 + em; if (e2 >= Ee) e2 = Ee - 1;
            s_n = srcs[e2]; d_n = dsts[e2]; d2nxt = d2buf[e2];
        }
        bar_lds();

        {
            f4_t a2[2][2];
            #pragma unroll
            for (int mm = 0; mm < 2; ++mm)
                #pragma unroll
                for (int h2 = 0; h2 < 2; ++h2) a2[mm][h2] = (f4_t){0.f,0.f,0.f,0.f};
            #pragma unroll
            for (int kc = 0; kc < 4; ++kc) {
                #pragma unroll
                for (int mm = 0; mm < 2; ++mm) {
                    const bf8_t a = *(const bf8_t*)&s_m1[(mg*32 + mm*16 + l15)*136 + quad*8 + kc*32];
                    a2[mm][0] = MFMA16(a, bW2[kc][0], a2[mm][0]);
                    a2[mm][1] = MFMA16(a, bW2[kc][1], a2[mm][1]);
                }
            }
            #pragma unroll
            for (int mm = 0; mm < 2; ++mm)
                #pragma unroll
                for (int i = 0; i < 4; ++i) {
                    const int m = mg*32 + mm*16 + quad*4 + i;
                    s_m2[m*136 + ng*32 + l15]      = (__bf16)silu_f(a2[mm][0][i] + be2v[0]);
                    s_m2[m*136 + ng*32 + 16 + l15] = (__bf16)silu_f(a2[mm][1][i] + be2v[1]);
                }
        }
        bar_lds();

        {
            const int ms = tid >> 4, c2 = tid & 15;
            *(bf8_t*)(m_buf + ((size_t)t*64 + ms)*H + c2*8) =
                *(const bf8_t*)&s_m2[ms*136 + c2*8];
            *(bf8_t*)(m_buf + ((size_t)t*64 + 32 + ms)*H + c2*8) =
                *(const bf8_t*)&s_m2[(ms+32)*136 + c2*8];
        }

        {
            f4_t a3[2][2];
            #pragma unroll
            for (int mm = 0; mm < 2; ++mm)
                #pragma unroll
                for (int h2 = 0; h2 < 2; ++h2) a3[mm][h2] = (f4_t){0.f,0.f,0.f,0.f};
            #pragma unroll
            for (int kc = 0; kc < 4; ++kc) {
                #pragma unroll
                for (int mm = 0; mm < 2; ++mm) {
                    const bf8_t a = *(const bf8_t*)&s_m2[(mg*32 + mm*16 + l15)*136 + quad*8 + kc*32];
                    a3[mm][0] = MFMA16(a, bWc[kc][0], a3[mm][0]);
                    a3[mm][1] = MFMA16(a, bWc[kc][1], a3[mm][1]);
                }
            }
            float p[2][4];
            #pragma unroll
            for (int mm = 0; mm < 2; ++mm)
                #pragma unroll
                for (int i = 0; i < 4; ++i) {
                    const float v0 = silu_f(a3[mm][0][i] + bc1v[0]);
                    const float v1 = silu_f(a3[mm][1][i] + bc1v[1]);
                    p[mm][i] = v0*wc2v[0] + v1*wc2v[1];
                }
            #pragma unroll
            for (int off = 1; off < 16; off <<= 1)
                #pragma unroll
                for (int mm = 0; mm < 2; ++mm)
                    #pragma unroll
                    for (int i = 0; i < 4; ++i) p[mm][i] += __shfl_xor(p[mm][i], off, 64);
            if (l15 == 0) {
                #pragma unroll
                for (int mm = 0; mm < 2; ++mm)
                    #pragma unroll
                    for (int i = 0; i < 4; ++i)
                        s_cw[(mg*32 + mm*16 + quad*4 + i)*4 + ng] = p[mm][i];
            }
        }
        bar_lds();

        if (tid < 64)
            cw_buf[(size_t)t*64 + tid] =
                s_cw[tid*4] + s_cw[tid*4+1] + s_cw[tid*4+2] + s_cw[tid*4+3];
    }
}

// ---------------------------------------------------------------------------
// Aggregation: one wave per node, fully sequential streaming of sorted
// m_buf/cw/rel4 (no gathers). Writes msg (bf16) and x_out.
// ---------------------------------------------------------------------------
__global__ __launch_bounds__(512)
void egnn_agg_kernel(const void* __restrict__ x, const int* __restrict__ off,
                     const __bf16* __restrict__ m_buf, const float* __restrict__ cw_buf,
                     const float4* __restrict__ rel4, __bf16* __restrict__ msgb,
                     const int* __restrict__ flags, void* __restrict__ out,
                     size_t obase, int Nn)
{
    const bool f32 = flags[0] != 0;
    const int wv = threadIdx.x >> 6, lane = threadIdx.x & 63;
    const int n = blockIdx.x*8 + wv;
    if (n >= Nn) return;
    const int p0 = off[n], p1 = off[n+1];

    float ms0 = 0.f, ms1 = 0.f, c0 = 0.f, c1 = 0.f, c2 = 0.f;
    const unsigned int* mb = (const unsigned int*)m_buf;
    for (int p = p0; p < p1; ++p) {
        const unsigned int u = mb[(size_t)p*64 + lane];
        ms0 += __uint_as_float(u << 16);
        ms1 += __uint_as_float(u & 0xffff0000u);
        const float cw = cw_buf[p];
        const float4 r = rel4[p];
        c0 += r.x*cw; c1 += r.y*cw; c2 += r.z*cw;
    }
    // pack two bf16 and store 4B per lane (coalesced)
    union { unsigned int u; __bf16 b[2]; } pk;
    pk.b[0] = (__bf16)ms0; pk.b[1] = (__bf16)ms1;
    *(unsigned int*)&msgb[(size_t)n*H + 2*lane] = pk.u;
    if (lane == 0) {
        float xd0, xd1, xd2;
        if (f32) { const float* xp = (const float*)x + (size_t)n*3; xd0=xp[0]; xd1=xp[1]; xd2=xp[2]; }
        else     { const __bf16* xp = (const __bf16*)x + (size_t)n*3; xd0=(float)xp[0]; xd1=(float)xp[1]; xd2=(float)xp[2]; }
        const float o0 = xd0 + c0, o1 = xd1 + c1, o2 = xd2 + c2;
        if (f32) {
            float* op = (float*)out + obase + (size_t)n*3;
            op[0] = o0; op[1] = o1; op[2] = o2;
        } else {
            __bf16* op = (__bf16*)out + obase + (size_t)n*3;
            op[0] = (__bf16)o0; op[1] = (__bf16)o1; op[2] = (__bf16)o2;
        }
    }
}

// ---------------------------------------------------------------------------
// Node kernel: h_out = h + silu([h | msg] @ Wn1 + bn1) @ Wn2 + bn2
// msg is bf16 (CSR path) or f32 (fallback path) per msg_f32 arg.
// ---------------------------------------------------------------------------
__global__ __launch_bounds__(512, 2)
void egnn_node_kernel(const void* __restrict__ h, const void* __restrict__ msg,
                      const void* __restrict__ Wn1, const void* __restrict__ bn1,
                      const void* __restrict__ Wn2, const void* __restrict__ bn2,
                      const int* __restrict__ flags, void* __restrict__ h_out,
                      int Nn, int msg_f32)
{
    const bool f32 = flags[0] != 0;
    const int tid  = threadIdx.x;
    const int wv   = tid >> 6;
    const int lane = tid & 63;
    const int quad = lane >> 4;
    const int l15  = lane & 15;
    const int mg   = wv >> 2;
    const int ng   = wv & 3;

    bf8_t bW1[8][2];
    bf8_t bW2[4][2];
    float b1v[2], b2v[2];
    #pragma unroll
    for (int t = 0; t < 2; ++t) {
        const int n = ng*32 + t*16 + l15;
        #pragma unroll
        for (int kc = 0; kc < 8; ++kc) {
            bf8_t v;
            #pragma unroll
            for (int j = 0; j < 8; ++j) v[j] = (__bf16)wload(Wn1, (kc*32 + quad*8 + j)*H + n, f32);
            bW1[kc][t] = v;
        }
        #pragma unroll
        for (int kc = 0; kc < 4; ++kc) {
            bf8_t v;
            #pragma unroll
            for (int j = 0; j < 8; ++j) v[j] = (__bf16)wload(Wn2, (kc*32 + quad*8 + j)*H + n, f32);
            bW2[kc][t] = v;
        }
        b1v[t] = wload(bn1, n, f32);
        b2v[t] = wload(bn2, n, f32);
    }

    __shared__ __bf16 s_in[32*264];
    __shared__ __bf16 s_t1[32*136];

    const int tiles = (Nn + 31) >> 5;
    for (int tile = blockIdx.x; tile < tiles; tile += gridDim.x) {
        const int nb = tile << 5;
        __syncthreads();
        #pragma unroll
        for (int r = 0; r < 2; ++r) {
            const int idx = tid + r*512;
            const int m = idx >> 5, c = idx & 31;
            int node = nb + m;
            if (node >= Nn) node = Nn - 1;
            if (c < 16) {
                *(bf8_t*)&s_in[m*264 + c*8] = hload8(h, (size_t)node*H + c*8, f32);
            } else if (msg_f32) {
                const float4* mp = (const float4*)((const float*)msg + (size_t)node*H + (c - 16)*8);
                const float4 v0 = mp[0], v1 = mp[1];
                __bf16* d = &s_in[m*264 + c*8];
                d[0] = (__bf16)v0.x; d[1] = (__bf16)v0.y; d[2] = (__bf16)v0.z; d[3] = (__bf16)v0.w;
                d[4] = (__bf16)v1.x; d[5] = (__bf16)v1.y; d[6] = (__bf16)v1.z; d[7] = (__bf16)v1.w;
            } else {
                *(bf8_t*)&s_in[m*264 + c*8] =
                    *(const bf8_t*)((const __bf16*)msg + (size_t)node*H + (c - 16)*8);
            }
        }
        __syncthreads();

        {
            f4_t a0 = {0.f,0.f,0.f,0.f}, a1 = {0.f,0.f,0.f,0.f};
            const int abase = (mg*16 + l15)*264 + quad*8;
            #pragma unroll
            for (int kc = 0; kc < 8; ++kc) {
                const bf8_t a = *(const bf8_t*)&s_in[abase + kc*32];
                a0 = MFMA16(a, bW1[kc][0], a0);
                a1 = MFMA16(a, bW1[kc][1], a1);
            }
            #pragma unroll
            for (int i = 0; i < 4; ++i) {
                const int m = mg*16 + quad*4 + i;
                s_t1[m*136 + ng*32 + l15]      = (__bf16)silu_f(a0[i] + b1v[0]);
                s_t1[m*136 + ng*32 + 16 + l15] = (__bf16)silu_f(a1[i] + b1v[1]);
            }
        }
        __syncthreads();

        {
            f4_t a0 = {0.f,0.f,0.f,0.f}, a1 = {0.f,0.f,0.f,0.f};
            const int abase = (mg*16 + l15)*136 + quad*8;
            #pragma unroll
            for (int kc = 0; kc < 4; ++kc) {
                const bf8_t a = *(const bf8_t*)&s_t1[abase + kc*32];
                a0 = MFMA16(a, bW2[kc][0], a0);
                a1 = MFMA16(a, bW2[kc][1], a1);
            }
            #pragma unroll
            for (int i = 0; i < 4; ++i) {
                const int node = nb + mg*16 + quad*4 + i;
                if (node < Nn) {
                    const int n0 = ng*32 + l15, n1 = n0 + 16;
                    const size_t i0 = (size_t)node*H + n0, i1 = (size_t)node*H + n1;
                    const float h0 = f32 ? ((const float*)h)[i0] : (float)((const __bf16*)h)[i0];
                    const float h1 = f32 ? ((const float*)h)[i1] : (float)((const __bf16*)h)[i1];
                    const float o0 = a0[i] + b2v[0] + h0;
                    const float o1 = a1[i] + b2v[1] + h1;
                    if (f32) {
                        ((float*)h_out)[i0] = o0;
                        ((float*)h_out)[i1] = o1;
                    } else {
                        ((__bf16*)h_out)[i0] = (__bf16)o0;
                        ((__bf16*)h_out)[i1] = (__bf16)o1;
                    }
                }
            }
        }
    }
}

// ---------------------------------------------------------------------------
// Fallback (R2 atomic path)
// ---------------------------------------------------------------------------
__global__ void cvt_ei_kernel(const void* __restrict__ src, int* __restrict__ dst,
                              int n, const int* __restrict__ flags)
{
    const int i = blockIdx.x*blockDim.x + threadIdx.x;
    if (i >= n) return;
    dst[i] = flags[1] ? (int)((const long long*)src)[i] : ((const int*)src)[i];
}

__global__ __launch_bounds__(512, 2)
void egnn_edge_kernel(const void* __restrict__ h, const void* __restrict__ x,
                      const int* __restrict__ ei,
                      const void* __restrict__ We1, const void* __restrict__ be1,
                      const void* __restrict__ We2, const void* __restrict__ be2,
                      const void* __restrict__ Wc1, const void* __restrict__ bc1,
                      const void* __restrict__ Wc2, const int* __restrict__ flags,
                      float* __restrict__ msg_agg, float* __restrict__ coord_agg,
                      int Nn, int Ee)
{
    const bool f32 = flags[0] != 0;
    const int tid  = threadIdx.x;
    const int wv   = tid >> 6;
    const int lane = tid & 63;
    const int quad = lane >> 4;
    const int l15  = lane & 15;
    const int mg   = wv >> 2;
    const int ng   = wv & 3;

    bf8_t bW1[8][2];
    bf8_t bW2[4][2];
    bf8_t bWc[4][2];
    float be1v[2], be2v[2], bc1v[2], w1dv[2], wc2v[2];
    #pragma unroll
    for (int t = 0; t < 2; ++t) {
        const int n = ng*32 + t*16 + l15;
        #pragma unroll
        for (int kc = 0; kc < 8; ++kc) {
            bf8_t v;
            #pragma unroll
            for (int j = 0; j < 8; ++j) v[j] = (__bf16)wload(We1, (kc*32 + quad*8 + j)*H + n, f32);
            bW1[kc][t] = v;
        }
        #pragma unroll
        for (int kc = 0; kc < 4; ++kc) {
            bf8_t v, u;
            #pragma unroll
            for (int j = 0; j < 8; ++j) {
                v[j] = (__bf16)wload(We2, (kc*32 + quad*8 + j)*H + n, f32);
                u[j] = (__bf16)wload(Wc1, (kc*32 + quad*8 + j)*H + n, f32);
            }
            bW2[kc][t] = v;
            bWc[kc][t] = u;
        }
        be1v[t] = wload(be1, n, f32);
        be2v[t] = wload(be2, n, f32);
        bc1v[t] = wload(bc1, n, f32);
        w1dv[t] = wload(We1, 256*H + n, f32);
        wc2v[t] = wload(Wc2, n, f32);
    }

    __shared__ __bf16 s_in[32*264];
    __shared__ __bf16 s_m1[32*136];
    __shared__ __bf16 s_m2[32*136];
    __shared__ float  s_rel[32*3];
    __shared__ float  s_dist[32];
    __shared__ int    s_dstv[32];
    __shared__ float  s_cw[32*4];

    const int tiles = Ee >> 5;
    for (int tile = blockIdx.x; tile < tiles; tile += gridDim.x) {
        const int ebase = tile << 5;
        __syncthreads();

        if (tid < 32) {
            const int e  = ebase + tid;
            const int sn = ei[e];
            const int dn = ei[Ee + e];
            s_dstv[tid] = dn;
            float d2 = 0.f;
            #pragma unroll
            for (int c = 0; c < 3; ++c) {
                float r;
                if (f32) r = ((const float*)x)[sn*3 + c] - ((const float*)x)[dn*3 + c];
                else     r = (float)((const __bf16*)x)[sn*3 + c] - (float)((const __bf16*)x)[dn*3 + c];
                s_rel[tid*3 + c] = r;
                d2 += r*r;
            }
            s_dist[tid] = d2;
        }
        #pragma unroll
        for (int r = 0; r < 2; ++r) {
            const int idx = tid + r*512;
            const int m = idx >> 5, c = idx & 31;
            const int e = ebase + m;
            const int node = (c < 16) ? ei[e] : ei[Ee + e];
            *(bf8_t*)&s_in[m*264 + c*8] = hload8(h, (size_t)node*H + (c & 15)*8, f32);
        }
        __syncthreads();

        {
            f4_t a0 = {0.f,0.f,0.f,0.f}, a1 = {0.f,0.f,0.f,0.f};
            const int abase = (mg*16 + l15)*264 + quad*8;
            #pragma unroll
            for (int kc = 0; kc < 8; ++kc) {
                const bf8_t a = *(const bf8_t*)&s_in[abase + kc*32];
                a0 = MFMA16(a, bW1[kc][0], a0);
                a1 = MFMA16(a, bW1[kc][1], a1);
            }
            #pragma unroll
            for (int i = 0; i < 4; ++i) {
                const int m = mg*16 + quad*4 + i;
                const float d2 = s_dist[m];
                s_m1[m*136 + ng*32 + l15]      = (__bf16)silu_f(a0[i] + d2*w1dv[0] + be1v[0]);
                s_m1[m*136 + ng*32 + 16 + l15] = (__bf16)silu_f(a1[i] + d2*w1dv[1] + be1v[1]);
            }
        }
        __syncthreads();

        {
            f4_t a0 = {0.f,0.f,0.f,0.f}, a1 = {0.f,0.f,0.f,0.f};
            const int abase = (mg*16 + l15)*136 + quad*8;
            #pragma unroll
            for (int kc = 0; kc < 4; ++kc) {
                const bf8_t a = *(const bf8_t*)&s_m1[abase + kc*32];
                a0 = MFMA16(a, bW2[kc][0], a0);
                a1 = MFMA16(a, bW2[kc][1], a1);
            }
            #pragma unroll
            for (int i = 0; i < 4; ++i) {
                const int m = mg*16 + quad*4 + i;
                const float v0 = silu_f(a0[i] + be2v[0]);
                const float v1 = silu_f(a1[i] + be2v[1]);
                s_m2[m*136 + ng*32 + l15]      = (__bf16)v0;
                s_m2[m*136 + ng*32 + 16 + l15] = (__bf16)v1;
                const size_t db = (size_t)s_dstv[m]*H + ng*32 + l15;
                atomicAdd(&msg_agg[db],      v0);
                atomicAdd(&msg_agg[db + 16], v1);
            }
        }
        __syncthreads();

        {
            f4_t a0 = {0.f,0.f,0.f,0.f}, a1 = {0.f,0.f,0.f,0.f};
            const int abase = (mg*16 + l15)*136 + quad*8;
            #pragma unroll
            for (int kc = 0; kc < 4; ++kc) {
                const bf8_t a = *(const bf8_t*)&s_m2[abase + kc*32];
                a0 = MFMA16(a, bWc[kc][0], a0);
                a1 = MFMA16(a, bWc[kc][1], a1);
            }
            float p[4];
            #pragma unroll
            for (int i = 0; i < 4; ++i) {
                const float v0 = silu_f(a0[i] + bc1v[0]);
                const float v1 = silu_f(a1[i] + bc1v[1]);
                p[i] = v0*wc2v[0] + v1*wc2v[1];
            }
            #pragma unroll
            for (int off = 1; off < 16; off <<= 1) {
                #pragma unroll
                for (int i = 0; i < 4; ++i) p[i] += __shfl_xor(p[i], off, 64);
            }
            if (l15 == 0) {
                #pragma unroll
                for (int i = 0; i < 4; ++i)
                    s_cw[(mg*16 + quad*4 + i)*4 + ng] = p[i];
            }
        }
        __syncthreads();

        if (tid < 96) {
            const int m = tid / 3, c = tid - m*3;
            const float cw = s_cw[m*4 + 0] + s_cw[m*4 + 1] + s_cw[m*4 + 2] + s_cw[m*4 + 3];
            atomicAdd(&coord_agg[(size_t)s_dstv[m]*3 + c], s_rel[m*3 + c]*cw);
        }
    }
}

__global__ void egnn_x_kernel(const void* __restrict__ x, const float* __restrict__ coord_agg,
                              const int* __restrict__ flags, void* __restrict__ out,
                              size_t obase, int total)
{
    const bool f32 = flags[0] != 0;
    const int i = blockIdx.x*blockDim.x + threadIdx.x;
    if (i >= total) return;
    const float xv = f32 ? ((const float*)x)[i] : (float)((const __bf16*)x)[i];
    const float o = xv + coord_agg[i];
    if (f32) ((float*)out)[obase + i] = o;
    else     ((__bf16*)out)[obase + i] = (__bf16)o;
}

static inline size_t align256(size_t v) { return (v + 255) & ~(size_t)255; }

extern "C" void kernel_launch(void* const* d_in, const int* in_sizes, int n_in,
                              void* d_out, int out_size, void* d_ws, size_t ws_size,
                              hipStream_t stream)
{
    const void* h   = d_in[0];
    const void* x   = d_in[1];
    const void* ei0 = d_in[2];
    const void* We1 = d_in[3];
    const void* be1 = d_in[4];
    const void* We2 = d_in[5];
    const void* be2 = d_in[6];
    const void* Wc1 = d_in[7];
    const void* bc1 = d_in[8];
    const void* Wc2 = d_in[9];
    const void* Wn1 = d_in[10];
    const void* bn1 = d_in[11];
    const void* Wn2 = d_in[12];
    const void* bn2 = d_in[13];

    const int Nn = in_sizes[0] / H;   // 50000
    const int Ee = in_sizes[2] / 2;   // 640000
    const int EeP = ((Ee + 63) & ~63) + 64;

    char* ws = (char*)d_ws;
    size_t o = 0;
    size_t o_mbuf  = o; o = align256(o + (size_t)EeP*H*2);     // m_ij bf16 (sorted)
    size_t o_msg   = o; o = align256(o + (size_t)Nn*H*2);      // msg bf16
    size_t o_srcs  = o; o = align256(o + (size_t)Ee*4);
    size_t o_dsts  = o; o = align256(o + (size_t)Ee*4);
    size_t o_cw    = o; o = align256(o + (size_t)EeP*4);
    size_t o_d2    = o; o = align256(o + (size_t)Ee*4);
    size_t o_rel   = o; o = align256(o + (size_t)Ee*16);       // rel4 (xyz,d2)
    size_t o_pb    = o; o = align256(o + (size_t)Nn*256*2);    // PB bf16 [N,256]
    size_t o_cnt   = o; o = align256(o + (size_t)Nn*4);
    size_t o_off   = o; o = align256(o + (size_t)(Nn+1)*4);
    size_t o_cur   = o; o = align256(o + (size_t)Nn*4);
    size_t o_bsum  = o; o = align256(o + 512*4);
    size_t o_base  = o; o = align256(o + 512*4);
    size_t o_flags = o; o = align256(o + 64);
    const size_t need_csr = o;

    const int nCh = (Nn + 1 + 511) / 512;

    if (ws_size >= need_csr) {
        __bf16* m_buf   = (__bf16*)(ws + o_mbuf);
        __bf16* msgb    = (__bf16*)(ws + o_msg);
        int*    srcs    = (int*)   (ws + o_srcs);
        int*    dsts    = (int*)   (ws + o_dsts);
        float*  cw_buf  = (float*) (ws + o_cw);
        float*  d2buf   = (float*) (ws + o_d2);
        float4* rel4    = (float4*)(ws + o_rel);
        __bf16* PB      = (__bf16*)(ws + o_pb);
        int*    cnt     = (int*)   (ws + o_cnt);
        int*    off     = (int*)   (ws + o_off);
        int*    cursor  = (int*)   (ws + o_cur);
        int*    bsum    = (int*)   (ws + o_bsum);
        int*    base    = (int*)   (ws + o_base);
        int*    flags   = (int*)   (ws + o_flags);

        detect_kernel<<<1, 256, 0, stream>>>((const unsigned short*)h, (const int*)ei0, flags);
        hipMemsetAsync(cnt, 0, (size_t)Nn*4, stream);
        histd_kernel<<<(Ee + 511)/512, 512, 0, stream>>>(ei0, cnt, flags, Ee);
        scanA_kernel<<<nCh, 512, 0, stream>>>(cnt, bsum, Nn);
        scanB_kernel<<<1, 64, 0, stream>>>(bsum, base, nCh);
        scanC_kernel<<<nCh, 512, 0, stream>>>(cnt, base, off, cursor, Nn);
        scatgeo_kernel<<<(Ee + 511)/512, 512, 0, stream>>>(ei0, cursor, srcs, dsts,
                                                           d2buf, rel4, x, flags, Ee);
        proj_kernel<<<1024, 512, 0, stream>>>(h, We1, be1, flags, PB, Nn);

        // grid 1024 -> 4 blocks/CU (LDS-capped), 32 waves/CU, 4 independent
        // barrier groups per CU (was 512 -> 2 blocks/CU, correlated stalls)
        egnn_edge_pipe_kernel<<<1024, 512, 0, stream>>>(PB, srcs, dsts, d2buf,
                                                        We1, We2, be2, Wc1, bc1, Wc2,
                                                        flags, m_buf, cw_buf, Ee);

        egnn_agg_kernel<<<(Nn + 7)/8, 512, 0, stream>>>(x, off, m_buf, cw_buf, rel4,
                                                        msgb, flags, d_out, (size_t)Nn*H, Nn);
        egnn_node_kernel<<<1024, 512, 0, stream>>>(h, msgb, Wn1, bn1, Wn2, bn2,
                                                   flags, d_out, Nn, 0);
    } else {
        // fallback: proven R2 atomic path
        float* msg_agg   = (float*)ws;
        float* coord_agg = (float*)(ws + (size_t)Nn*H*4);
        int*   ei        = (int*)  (ws + (size_t)Nn*H*4 + (size_t)Nn*3*4);
        int*   flags     = (int*)  (ws + (size_t)Nn*H*4 + (size_t)Nn*3*4 + (size_t)2*Ee*4);

        detect_kernel<<<1, 256, 0, stream>>>((const unsigned short*)h, (const int*)ei0, flags);
        cvt_ei_kernel<<<(2*Ee + 255)/256, 256, 0, stream>>>(ei0, ei, 2*Ee, flags);
        hipMemsetAsync(msg_agg,   0, (size_t)Nn*H*4, stream);
        hipMemsetAsync(coord_agg, 0, (size_t)Nn*3*4, stream);
        egnn_edge_kernel<<<1024, 512, 0, stream>>>(h, x, ei, We1, be1, We2, be2,
                                                   Wc1, bc1, Wc2, flags,
                                                   msg_agg, coord_agg, Nn, Ee);
        egnn_node_kernel<<<512, 512, 0, stream>>>(h, msg_agg, Wn1, bn1, Wn2, bn2,
                                                  flags, d_out, Nn, 1);
        egnn_x_kernel<<<(Nn*3 + 255)/256, 256, 0, stream>>>(x, coord_agg, flags, d_out,
                                                            (size_t)Nn*H, Nn*3);
    }
}

// Round 7
// 673.074 us; speedup vs baseline: 1.1175x; 1.1175x over previous
//
#include <hip/hip_runtime.h>

#define H 128

typedef __bf16 bf8_t __attribute__((ext_vector_type(8)));
typedef float  f4_t  __attribute__((ext_vector_type(4)));

#define MFMA16(a, b, c) __builtin_amdgcn_mfma_f32_16x16x32_bf16((a), (b), (c), 0, 0, 0)

__device__ __forceinline__ float silu_f(float v) {
    return v * (1.0f / (1.0f + __expf(-v)));
}

// LDS-only barrier: does NOT drain vmcnt, so global prefetch stays in flight.
__device__ __forceinline__ void bar_lds() {
    asm volatile("s_waitcnt lgkmcnt(0)\ns_barrier" ::: "memory");
}

__device__ __forceinline__ float wload(const void* p, int idx, bool f32) {
    return f32 ? ((const float*)p)[idx] : (float)((const __bf16*)p)[idx];
}

__device__ __forceinline__ bf8_t hload8(const void* p, size_t off, bool f32) {
    bf8_t v;
    if (f32) {
        const float4* q = (const float4*)((const float*)p + off);
        const float4 a = q[0], b = q[1];
        v[0]=(__bf16)a.x; v[1]=(__bf16)a.y; v[2]=(__bf16)a.z; v[3]=(__bf16)a.w;
        v[4]=(__bf16)b.x; v[5]=(__bf16)b.y; v[6]=(__bf16)b.z; v[7]=(__bf16)b.w;
    } else {
        v = *(const bf8_t*)((const __bf16*)p + off);
    }
    return v;
}

__device__ __forceinline__ int eidx(const void* ei, int i, bool i64) {
    return i64 ? (int)((const long long*)ei)[i] : ((const int*)ei)[i];
}

// ---------------------------------------------------------------------------
// dtype detection
// ---------------------------------------------------------------------------
__global__ void detect_kernel(const unsigned short* __restrict__ hraw,
                              const int* __restrict__ eiraw, int* __restrict__ flags)
{
    __shared__ int s_nf, s_oddnz;
    if (threadIdx.x == 0) { s_nf = 0; s_oddnz = 0; }
    __syncthreads();
    int nf = 0;
    for (int i = threadIdx.x; i < 16384; i += blockDim.x) {
        const unsigned short u = hraw[i];
        if (((u >> 7) & 0xFF) == 0xFF) nf++;
    }
    int onz = 0;
    for (int i = threadIdx.x; i < 512; i += blockDim.x) {
        if (eiraw[2*i + 1] != 0) onz++;
    }
    if (nf)  atomicAdd(&s_nf, nf);
    if (onz) atomicAdd(&s_oddnz, onz);
    __syncthreads();
    if (threadIdx.x == 0) {
        flags[0] = (s_nf > 0) ? 1 : 0;
        flags[1] = (s_oddnz == 0) ? 1 : 0;
    }
}

// ---------------------------------------------------------------------------
// CSR build: dst histogram (raw ei) -> scan -> scatter+geometry (fused)
// ---------------------------------------------------------------------------
__global__ void histd_kernel(const void* __restrict__ ei, int* __restrict__ cnt,
                             const int* __restrict__ flags, int Ee)
{
    const int e = blockIdx.x*blockDim.x + threadIdx.x;
    if (e < Ee) atomicAdd(&cnt[eidx(ei, Ee + e, flags[1] != 0)], 1);
}

__global__ void scanA_kernel(const int* __restrict__ cnt, int* __restrict__ bsum, int Nn)
{
    __shared__ int s[512];
    const int gi = blockIdx.x*512 + threadIdx.x;
    s[threadIdx.x] = (gi < Nn) ? cnt[gi] : 0;
    __syncthreads();
    for (int off = 256; off > 0; off >>= 1) {
        if (threadIdx.x < off) s[threadIdx.x] += s[threadIdx.x + off];
        __syncthreads();
    }
    if (threadIdx.x == 0) bsum[blockIdx.x] = s[0];
}

__global__ void scanB_kernel(int* __restrict__ bsum, int* __restrict__ base, int nCh)
{
    if (threadIdx.x == 0) {
        int acc = 0;
        for (int b = 0; b < nCh; ++b) { base[b] = acc; acc += bsum[b]; }
    }
}

__global__ void scanC_kernel(const int* __restrict__ cnt, const int* __restrict__ base,
                             int* __restrict__ off, int* __restrict__ cursor, int Nn)
{
    __shared__ int s[512];
    const int i  = threadIdx.x;
    const int gi = blockIdx.x*512 + i;
    const int v  = (gi < Nn) ? cnt[gi] : 0;
    s[i] = v;
    __syncthreads();
    for (int o = 1; o < 512; o <<= 1) {
        const int t = (i >= o) ? s[i - o] : 0;
        __syncthreads();
        s[i] += t;
        __syncthreads();
    }
    const int excl = s[i] - v;
    if (gi <= Nn) {
        const int val = base[blockIdx.x] + excl;
        off[gi] = val;
        if (gi < Nn) cursor[gi] = val;
    }
}

// scatter + geometry: compute sorted slot, write srcs/dsts/rel4 at slot
__global__ void scatgeo_kernel(const void* __restrict__ ei, int* __restrict__ cursor,
                               int* __restrict__ srcs, int* __restrict__ dsts,
                               float4* __restrict__ rel4, const void* __restrict__ x,
                               const int* __restrict__ flags, int Ee)
{
    const int e = blockIdx.x*blockDim.x + threadIdx.x;
    if (e >= Ee) return;
    const bool i64 = flags[1] != 0;
    const bool f32 = flags[0] != 0;
    const int s = eidx(ei, e, i64);
    const int d = eidx(ei, Ee + e, i64);
    const int p = atomicAdd(&cursor[d], 1);
    srcs[p] = s;
    dsts[p] = d;
    float r[3];
    #pragma unroll
    for (int c = 0; c < 3; ++c)
        r[c] = wload(x, s*3 + c, f32) - wload(x, d*3 + c, f32);
    float4 o; o.x = r[0]; o.y = r[1]; o.z = r[2];
    o.w = r[0]*r[0] + r[1]*r[1] + r[2]*r[2];
    rel4[p] = o;
}

// ---------------------------------------------------------------------------
// Projection kernel: PB[n][0:128]   = (h @ We1[0:128])[n]
//                    PB[n][128:256] = (h @ We1[128:256])[n] + be1
// ---------------------------------------------------------------------------
__global__ __launch_bounds__(512, 2)
void proj_kernel(const void* __restrict__ h, const void* __restrict__ We1,
                 const void* __restrict__ be1, const int* __restrict__ flags,
                 __bf16* __restrict__ PB, int Nn)
{
    const bool f32 = flags[0] != 0;
    const int tid  = threadIdx.x;
    const int wv   = tid >> 6;
    const int lane = tid & 63;
    const int quad = lane >> 4;
    const int l15  = lane & 15;

    bf8_t bW[4][2];
    float bias[2];
    #pragma unroll
    for (int t = 0; t < 2; ++t) {
        const int n    = wv*32 + t*16 + l15;
        const int rb   = (n < 128) ? 0 : 128;
        const int col  = n & 127;
        #pragma unroll
        for (int kc = 0; kc < 4; ++kc) {
            bf8_t v;
            #pragma unroll
            for (int j = 0; j < 8; ++j)
                v[j] = (__bf16)wload(We1, (rb + kc*32 + quad*8 + j)*H + col, f32);
            bW[kc][t] = v;
        }
        bias[t] = (n < 128) ? 0.f : wload(be1, col, f32);
    }

    __shared__ __bf16 s_h[32*136];

    const int tiles = (Nn + 31) >> 5;
    for (int tile = blockIdx.x; tile < tiles; tile += gridDim.x) {
        const int nb = tile << 5;
        __syncthreads();
        {
            const int m = tid >> 4, c = tid & 15;
            int node = nb + m; if (node >= Nn) node = Nn - 1;
            *(bf8_t*)&s_h[m*136 + c*8] = hload8(h, (size_t)node*H + c*8, f32);
        }
        __syncthreads();

        f4_t acc[2][2];
        #pragma unroll
        for (int mm = 0; mm < 2; ++mm)
            #pragma unroll
            for (int t = 0; t < 2; ++t) acc[mm][t] = (f4_t){0.f,0.f,0.f,0.f};
        #pragma unroll
        for (int kc = 0; kc < 4; ++kc) {
            #pragma unroll
            for (int mm = 0; mm < 2; ++mm) {
                const bf8_t a = *(const bf8_t*)&s_h[(mm*16 + l15)*136 + quad*8 + kc*32];
                acc[mm][0] = MFMA16(a, bW[kc][0], acc[mm][0]);
                acc[mm][1] = MFMA16(a, bW[kc][1], acc[mm][1]);
            }
        }
        #pragma unroll
        for (int mm = 0; mm < 2; ++mm)
            #pragma unroll
            for (int i = 0; i < 4; ++i) {
                const int row = nb + mm*16 + quad*4 + i;
                if (row < Nn) {
                    #pragma unroll
                    for (int t = 0; t < 2; ++t)
                        PB[(size_t)row*256 + wv*32 + t*16 + l15] =
                            (__bf16)(acc[mm][t][i] + bias[t]);
                }
            }
    }
}

// ---------------------------------------------------------------------------
// Edge kernel: 64-edge dst-sorted tiles, 3 lgkm-only barriers per tile.
// Layer 1 = gather PB rows + add + d2*w1d + silu. Layers 2/3 = MFMA.
// NEW: in-kernel segmented reduction of m_ij (msg) and rel*cw (coord) over
// the sorted dst-runs: interior runs -> plain stores (exactly-once),
// tile-boundary runs -> f32 atomics. m_buf eliminated entirely.
// ---------------------------------------------------------------------------
__global__ __launch_bounds__(512, 2)
void egnn_edge_pipe_kernel(const __bf16* __restrict__ PB,
                           const int* __restrict__ srcs, const int* __restrict__ dsts,
                           const float4* __restrict__ rel4,
                           const void* __restrict__ We1,  // row 256 only (w1d)
                           const void* __restrict__ We2, const void* __restrict__ be2,
                           const void* __restrict__ Wc1, const void* __restrict__ bc1,
                           const void* __restrict__ Wc2, const int* __restrict__ flags,
                           float* __restrict__ msg, float* __restrict__ coord,
                           int Ee)
{
    const bool f32 = flags[0] != 0;
    const int tid  = threadIdx.x;
    const int wv   = tid >> 6;
    const int lane = tid & 63;
    const int quad = lane >> 4;
    const int l15  = lane & 15;
    const int mg   = wv >> 2;
    const int ng   = wv & 3;

    bf8_t bW2[4][2], bWc[4][2];
    float be2v[2], bc1v[2], wc2v[2];
    #pragma unroll
    for (int t = 0; t < 2; ++t) {
        const int n = ng*32 + t*16 + l15;
        #pragma unroll
        for (int kc = 0; kc < 4; ++kc) {
            bf8_t v, u;
            #pragma unroll
            for (int j = 0; j < 8; ++j) {
                v[j] = (__bf16)wload(We2, (kc*32 + quad*8 + j)*H + n, f32);
                u[j] = (__bf16)wload(Wc1, (kc*32 + quad*8 + j)*H + n, f32);
            }
            bW2[kc][t] = v;
            bWc[kc][t] = u;
        }
        be2v[t] = wload(be2, n, f32);
        bc1v[t] = wload(bc1, n, f32);
        wc2v[t] = wload(Wc2, n, f32);
    }

    const int em = tid >> 3;          // edge row 0..63
    const int ch = tid & 7;           // 2 column-chunks per thread
    float w1dA[8], w1dB[8];
    #pragma unroll
    for (int j = 0; j < 8; ++j) {
        w1dA[j] = wload(We1, 256*H + ch*8 + j, f32);
        w1dB[j] = wload(We1, 256*H + (ch+8)*8 + j, f32);
    }

    // msg-reduce roles
    const int rcol = tid >> 2;        // 0..127
    const int rg   = tid & 3;         // row group 0..3 (rows rg*16..+15)
    const int qb   = lane & ~3;       // quad base lane (same rcol)

    __shared__ __bf16 s_m1[64*136];
    __shared__ __bf16 s_m2[64*136];
    __shared__ float  s_cw[4*64];     // [ng][edge]
    __shared__ int    s_dst[2][64];
    __shared__ float4 s_rl[2][64];

    const int tiles = (Ee + 63) >> 6;
    const float* rw = (const float*)rel4;

    bf8_t rA0, rA1, rB0, rB1;
    float d2cur, d2nxt;
    int   s_n, d_n, d_c;
    float4 r4c, r4n;
    {
        int e0 = blockIdx.x*64 + em; if (e0 >= Ee) e0 = Ee - 1;
        const int sc = srcs[e0], dc = dsts[e0];
        d_c = dc;
        d2cur = rw[(size_t)e0*4 + 3];
        if (ch == 0) r4c = rel4[e0];
        rA0 = *(const bf8_t*)(PB + (size_t)sc*256 + ch*8);
        rA1 = *(const bf8_t*)(PB + (size_t)sc*256 + (ch+8)*8);
        rB0 = *(const bf8_t*)(PB + (size_t)dc*256 + 128 + ch*8);
        rB1 = *(const bf8_t*)(PB + (size_t)dc*256 + 128 + (ch+8)*8);
        const int t1 = blockIdx.x + gridDim.x;
        const int tt = (t1 < tiles) ? t1 : blockIdx.x;
        int e1 = tt*64 + em; if (e1 >= Ee) e1 = Ee - 1;
        s_n = srcs[e1]; d_n = dsts[e1]; d2nxt = rw[(size_t)e1*4 + 3];
        if (ch == 0) r4n = rel4[e1];
    }

    int li = 0;
    for (int t = blockIdx.x; t < tiles; t += gridDim.x, ++li) {
        const int sb = li & 1;
        // ---- stage layer-1 output + dst/rel staging ----
        {
            bf8_t o0, o1;
            #pragma unroll
            for (int j = 0; j < 8; ++j) {
                const float f0 = (float)rA0[j] + (float)rB0[j] + d2cur*w1dA[j];
                const float f1 = (float)rA1[j] + (float)rB1[j] + d2cur*w1dB[j];
                o0[j] = (__bf16)silu_f(f0);
                o1[j] = (__bf16)silu_f(f1);
            }
            *(bf8_t*)&s_m1[em*136 + ch*8]       = o0;
            *(bf8_t*)&s_m1[em*136 + (ch+8)*8]   = o1;
            if (ch == 0) { s_dst[sb][em] = d_c; s_rl[sb][em] = r4c; }
        }
        // ---- prefetch next tile ----
        {
            const int sc = s_n, dc2 = d_n;
            rA0 = *(const bf8_t*)(PB + (size_t)sc*256 + ch*8);
            rA1 = *(const bf8_t*)(PB + (size_t)sc*256 + (ch+8)*8);
            rB0 = *(const bf8_t*)(PB + (size_t)dc2*256 + 128 + ch*8);
            rB1 = *(const bf8_t*)(PB + (size_t)dc2*256 + 128 + (ch+8)*8);
            d_c = d_n; d2cur = d2nxt;
            if (ch == 0) r4c = r4n;
            const int t2 = t + 2*gridDim.x;
            const int tt = (t2 < tiles) ? t2 : t;
            int e2 = tt*64 + em; if (e2 >= Ee) e2 = Ee - 1;
            s_n = srcs[e2]; d_n = dsts[e2]; d2nxt = rw[(size_t)e2*4 + 3];
            if (ch == 0) r4n = rel4[e2];
        }
        bar_lds();

        // ---- layer 2: m2 = silu(m1 @ We2 + be2) ----
        {
            f4_t a2[2][2];
            #pragma unroll
            for (int mm = 0; mm < 2; ++mm)
                #pragma unroll
                for (int h2 = 0; h2 < 2; ++h2) a2[mm][h2] = (f4_t){0.f,0.f,0.f,0.f};
            #pragma unroll
            for (int kc = 0; kc < 4; ++kc) {
                #pragma unroll
                for (int mm = 0; mm < 2; ++mm) {
                    const bf8_t a = *(const bf8_t*)&s_m1[(mg*32 + mm*16 + l15)*136 + quad*8 + kc*32];
                    a2[mm][0] = MFMA16(a, bW2[kc][0], a2[mm][0]);
                    a2[mm][1] = MFMA16(a, bW2[kc][1], a2[mm][1]);
                }
            }
            #pragma unroll
            for (int mm = 0; mm < 2; ++mm)
                #pragma unroll
                for (int i = 0; i < 4; ++i) {
                    const int m = mg*32 + mm*16 + quad*4 + i;
                    s_m2[m*136 + ng*32 + l15]      = (__bf16)silu_f(a2[mm][0][i] + be2v[0]);
                    s_m2[m*136 + ng*32 + 16 + l15] = (__bf16)silu_f(a2[mm][1][i] + be2v[1]);
                }
        }
        bar_lds();

        // ---- layer 3: coord head partials ----
        {
            f4_t a3[2][2];
            #pragma unroll
            for (int mm = 0; mm < 2; ++mm)
                #pragma unroll
                for (int h2 = 0; h2 < 2; ++h2) a3[mm][h2] = (f4_t){0.f,0.f,0.f,0.f};
            #pragma unroll
            for (int kc = 0; kc < 4; ++kc) {
                #pragma unroll
                for (int mm = 0; mm < 2; ++mm) {
                    const bf8_t a = *(const bf8_t*)&s_m2[(mg*32 + mm*16 + l15)*136 + quad*8 + kc*32];
                    a3[mm][0] = MFMA16(a, bWc[kc][0], a3[mm][0]);
                    a3[mm][1] = MFMA16(a, bWc[kc][1], a3[mm][1]);
                }
            }
            float p[2][4];
            #pragma unroll
            for (int mm = 0; mm < 2; ++mm)
                #pragma unroll
                for (int i = 0; i < 4; ++i) {
                    const float v0 = silu_f(a3[mm][0][i] + bc1v[0]);
                    const float v1 = silu_f(a3[mm][1][i] + bc1v[1]);
                    p[mm][i] = v0*wc2v[0] + v1*wc2v[1];
                }
            #pragma unroll
            for (int off = 1; off < 16; off <<= 1)
                #pragma unroll
                for (int mm = 0; mm < 2; ++mm)
                    #pragma unroll
                    for (int i = 0; i < 4; ++i) p[mm][i] += __shfl_xor(p[mm][i], off, 64);
            if (l15 == 0) {
                #pragma unroll
                for (int mm = 0; mm < 2; ++mm)
                    #pragma unroll
                    for (int i = 0; i < 4; ++i)
                        s_cw[ng*64 + (mg*32 + mm*16 + quad*4 + i)] = p[mm][i];
            }
        }

        // ---- msg segmented reduce over dst-runs (reads s_m2, s_dst[sb]) ----
        {
            const int rbase = rg*16;
            int   curd = s_dst[sb][rbase];
            float acc  = 0.f;
            float pre  = 0.f;
            int   predone = 0;
            #pragma unroll
            for (int i = 0; i < 16; ++i) {
                const int   d = s_dst[sb][rbase + i];
                const float v = (float)s_m2[(rbase + i)*136 + rcol];
                if (d != curd) {
                    if (!predone) { pre = acc; predone = 1; }
                    else          { msg[(size_t)curd*H + rcol] = acc; }  // interior run
                    curd = d; acc = v;
                } else acc += v;
            }
            const float suf = acc;          // trailing run sum (dst = curd)
            const int   whf = !predone;     // whole group is one run
            // gather quad partials via shuffles (lanes qb..qb+3 share rcol)
            float preA[4], sufA[4]; int whA[4];
            #pragma unroll
            for (int gg = 0; gg < 4; ++gg) {
                preA[gg] = __shfl(pre, qb + gg, 64);
                sufA[gg] = __shfl(suf, qb + gg, 64);
                whA[gg]  = __shfl(whf, qb + gg, 64);
            }
            if (rg == 0) {
                int   curd2 = s_dst[sb][0];
                float cur   = 0.f;
                int   first = 1;
                #pragma unroll
                for (int gg = 0; gg < 4; ++gg) {
                    const int F = s_dst[sb][gg*16];
                    const int L = s_dst[sb][gg*16 + 15];
                    if (F != curd2) {
                        if (first) atomicAdd(&msg[(size_t)curd2*H + rcol], cur);
                        else       msg[(size_t)curd2*H + rcol] = cur;
                        first = 0; curd2 = F; cur = 0.f;
                    }
                    if (whA[gg]) {
                        cur += sufA[gg];
                    } else {
                        cur += preA[gg];
                        if (first) atomicAdd(&msg[(size_t)curd2*H + rcol], cur);
                        else       msg[(size_t)curd2*H + rcol] = cur;
                        first = 0; curd2 = L; cur = sufA[gg];
                    }
                }
                atomicAdd(&msg[(size_t)curd2*H + rcol], cur);  // last run: boundary
            }
        }
        bar_lds();

        // ---- coord segmented scan (wave 0): cw per edge, runs over dsts ----
        if (tid < 64) {
            const int e = tid;
            const float cwv = s_cw[e] + s_cw[64 + e] + s_cw[128 + e] + s_cw[192 + e];
            const float4 r = s_rl[sb][e];
            const int d = s_dst[sb][e];
            float vx = r.x*cwv, vy = r.y*cwv, vz = r.z*cwv;
            int   cn = 1;
            #pragma unroll
            for (int k = 1; k < 64; k <<= 1) {
                const int   dk = __shfl_up(d,  k, 64);
                const float xk = __shfl_up(vx, k, 64);
                const float yk = __shfl_up(vy, k, 64);
                const float zk = __shfl_up(vz, k, 64);
                const int   ck = __shfl_up(cn, k, 64);
                if (e >= k && dk == d) { vx += xk; vy += yk; vz += zk; cn += ck; }
            }
            const int dnx = __shfl_down(d, 1, 64);
            const bool runend = (e == 63) || (dnx != d);
            if (runend) {
                const int rs = e - cn + 1;
                if (rs == 0 || e == 63) {
                    atomicAdd(&coord[(size_t)d*3 + 0], vx);
                    atomicAdd(&coord[(size_t)d*3 + 1], vy);
                    atomicAdd(&coord[(size_t)d*3 + 2], vz);
                } else {
                    coord[(size_t)d*3 + 0] = vx;
                    coord[(size_t)d*3 + 1] = vy;
                    coord[(size_t)d*3 + 2] = vz;
                }
            }
        }
    }
}

// ---------------------------------------------------------------------------
// Node kernel: h_out = h + silu([h | msg] @ Wn1 + bn1) @ Wn2 + bn2
// msg is f32. Optionally also emits x_out = x + coord (do_x).
// ---------------------------------------------------------------------------
__global__ __launch_bounds__(512, 2)
void egnn_node_kernel(const void* __restrict__ h, const float* __restrict__ msg,
                      const void* __restrict__ Wn1, const void* __restrict__ bn1,
                      const void* __restrict__ Wn2, const void* __restrict__ bn2,
                      const int* __restrict__ flags, void* __restrict__ h_out,
                      const void* __restrict__ x, const float* __restrict__ coord,
                      size_t obase, int do_x, int Nn)
{
    const bool f32 = flags[0] != 0;
    const int tid  = threadIdx.x;
    const int wv   = tid >> 6;
    const int lane = tid & 63;
    const int quad = lane >> 4;
    const int l15  = lane & 15;
    const int mg   = wv >> 2;
    const int ng   = wv & 3;

    bf8_t bW1[8][2];
    bf8_t bW2[4][2];
    float b1v[2], b2v[2];
    #pragma unroll
    for (int t = 0; t < 2; ++t) {
        const int n = ng*32 + t*16 + l15;
        #pragma unroll
        for (int kc = 0; kc < 8; ++kc) {
            bf8_t v;
            #pragma unroll
            for (int j = 0; j < 8; ++j) v[j] = (__bf16)wload(Wn1, (kc*32 + quad*8 + j)*H + n, f32);
            bW1[kc][t] = v;
        }
        #pragma unroll
        for (int kc = 0; kc < 4; ++kc) {
            bf8_t v;
            #pragma unroll
            for (int j = 0; j < 8; ++j) v[j] = (__bf16)wload(Wn2, (kc*32 + quad*8 + j)*H + n, f32);
            bW2[kc][t] = v;
        }
        b1v[t] = wload(bn1, n, f32);
        b2v[t] = wload(bn2, n, f32);
    }

    __shared__ __bf16 s_in[32*264];
    __shared__ __bf16 s_t1[32*136];

    const int tiles = (Nn + 31) >> 5;
    for (int tile = blockIdx.x; tile < tiles; tile += gridDim.x) {
        const int nb = tile << 5;
        __syncthreads();
        #pragma unroll
        for (int r = 0; r < 2; ++r) {
            const int idx = tid + r*512;
            const int m = idx >> 5, c = idx & 31;
            int node = nb + m;
            if (node >= Nn) node = Nn - 1;
            if (c < 16) {
                *(bf8_t*)&s_in[m*264 + c*8] = hload8(h, (size_t)node*H + c*8, f32);
            } else {
                const float4* mp = (const float4*)(msg + (size_t)node*H + (c - 16)*8);
                const float4 v0 = mp[0], v1 = mp[1];
                __bf16* d = &s_in[m*264 + c*8];
                d[0] = (__bf16)v0.x; d[1] = (__bf16)v0.y; d[2] = (__bf16)v0.z; d[3] = (__bf16)v0.w;
                d[4] = (__bf16)v1.x; d[5] = (__bf16)v1.y; d[6] = (__bf16)v1.z; d[7] = (__bf16)v1.w;
            }
        }
        // x_out epilogue (independent of LDS)
        if (do_x && tid < 96) {
            const int m = tid / 3, c = tid - m*3;
            const int node = nb + m;
            if (node < Nn) {
                const float xv = wload(x, node*3 + c, f32);
                const float o = xv + coord[(size_t)node*3 + c];
                if (f32) ((float*)h_out)[obase + (size_t)node*3 + c] = o;
                else     ((__bf16*)h_out)[obase + (size_t)node*3 + c] = (__bf16)o;
            }
        }
        __syncthreads();

        {
            f4_t a0 = {0.f,0.f,0.f,0.f}, a1 = {0.f,0.f,0.f,0.f};
            const int abase = (mg*16 + l15)*264 + quad*8;
            #pragma unroll
            for (int kc = 0; kc < 8; ++kc) {
                const bf8_t a = *(const bf8_t*)&s_in[abase + kc*32];
                a0 = MFMA16(a, bW1[kc][0], a0);
                a1 = MFMA16(a, bW1[kc][1], a1);
            }
            #pragma unroll
            for (int i = 0; i < 4; ++i) {
                const int m = mg*16 + quad*4 + i;
                s_t1[m*136 + ng*32 + l15]      = (__bf16)silu_f(a0[i] + b1v[0]);
                s_t1[m*136 + ng*32 + 16 + l15] = (__bf16)silu_f(a1[i] + b1v[1]);
            }
        }
        __syncthreads();

        {
            f4_t a0 = {0.f,0.f,0.f,0.f}, a1 = {0.f,0.f,0.f,0.f};
            const int abase = (mg*16 + l15)*136 + quad*8;
            #pragma unroll
            for (int kc = 0; kc < 4; ++kc) {
                const bf8_t a = *(const bf8_t*)&s_t1[abase + kc*32];
                a0 = MFMA16(a, bW2[kc][0], a0);
                a1 = MFMA16(a, bW2[kc][1], a1);
            }
            #pragma unroll
            for (int i = 0; i < 4; ++i) {
                const int node = nb + mg*16 + quad*4 + i;
                if (node < Nn) {
                    const int n0 = ng*32 + l15, n1 = n0 + 16;
                    const size_t i0 = (size_t)node*H + n0, i1 = (size_t)node*H + n1;
                    const float h0 = f32 ? ((const float*)h)[i0] : (float)((const __bf16*)h)[i0];
                    const float h1 = f32 ? ((const float*)h)[i1] : (float)((const __bf16*)h)[i1];
                    const float o0 = a0[i] + b2v[0] + h0;
                    const float o1 = a1[i] + b2v[1] + h1;
                    if (f32) {
                        ((float*)h_out)[i0] = o0;
                        ((float*)h_out)[i1] = o1;
                    } else {
                        ((__bf16*)h_out)[i0] = (__bf16)o0;
                        ((__bf16*)h_out)[i1] = (__bf16)o1;
                    }
                }
            }
        }
    }
}

// ---------------------------------------------------------------------------
// Fallback (R2 atomic path)
// ---------------------------------------------------------------------------
__global__ void cvt_ei_kernel(const void* __restrict__ src, int* __restrict__ dst,
                              int n, const int* __restrict__ flags)
{
    const int i = blockIdx.x*blockDim.x + threadIdx.x;
    if (i >= n) return;
    dst[i] = flags[1] ? (int)((const long long*)src)[i] : ((const int*)src)[i];
}

__global__ __launch_bounds__(512, 2)
void egnn_edge_kernel(const void* __restrict__ h, const void* __restrict__ x,
                      const int* __restrict__ ei,
                      const void* __restrict__ We1, const void* __restrict__ be1,
                      const void* __restrict__ We2, const void* __restrict__ be2,
                      const void* __restrict__ Wc1, const void* __restrict__ bc1,
                      const void* __restrict__ Wc2, const int* __restrict__ flags,
                      float* __restrict__ msg_agg, float* __restrict__ coord_agg,
                      int Nn, int Ee)
{
    const bool f32 = flags[0] != 0;
    const int tid  = threadIdx.x;
    const int wv   = tid >> 6;
    const int lane = tid & 63;
    const int quad = lane >> 4;
    const int l15  = lane & 15;
    const int mg   = wv >> 2;
    const int ng   = wv & 3;

    bf8_t bW1[8][2];
    bf8_t bW2[4][2];
    bf8_t bWc[4][2];
    float be1v[2], be2v[2], bc1v[2], w1dv[2], wc2v[2];
    #pragma unroll
    for (int t = 0; t < 2; ++t) {
        const int n = ng*32 + t*16 + l15;
        #pragma unroll
        for (int kc = 0; kc < 8; ++kc) {
            bf8_t v;
            #pragma unroll
            for (int j = 0; j < 8; ++j) v[j] = (__bf16)wload(We1, (kc*32 + quad*8 + j)*H + n, f32);
            bW1[kc][t] = v;
        }
        #pragma unroll
        for (int kc = 0; kc < 4; ++kc) {
            bf8_t v, u;
            #pragma unroll
            for (int j = 0; j < 8; ++j) {
                v[j] = (__bf16)wload(We2, (kc*32 + quad*8 + j)*H + n, f32);
                u[j] = (__bf16)wload(Wc1, (kc*32 + quad*8 + j)*H + n, f32);
            }
            bW2[kc][t] = v;
            bWc[kc][t] = u;
        }
        be1v[t] = wload(be1, n, f32);
        be2v[t] = wload(be2, n, f32);
        bc1v[t] = wload(bc1, n, f32);
        w1dv[t] = wload(We1, 256*H + n, f32);
        wc2v[t] = wload(Wc2, n, f32);
    }

    __shared__ __bf16 s_in[32*264];
    __shared__ __bf16 s_m1[32*136];
    __shared__ __bf16 s_m2[32*136];
    __shared__ float  s_rel[32*3];
    __shared__ float  s_dist[32];
    __shared__ int    s_dstv[32];
    __shared__ float  s_cw[32*4];

    const int tiles = Ee >> 5;
    for (int tile = blockIdx.x; tile < tiles; tile += gridDim.x) {
        const int ebase = tile << 5;
        __syncthreads();

        if (tid < 32) {
            const int e  = ebase + tid;
            const int sn = ei[e];
            const int dn = ei[Ee + e];
            s_dstv[tid] = dn;
            float d2 = 0.f;
            #pragma unroll
            for (int c = 0; c < 3; ++c) {
                float r;
                if (f32) r = ((const float*)x)[sn*3 + c] - ((const float*)x)[dn*3 + c];
                else     r = (float)((const __bf16*)x)[sn*3 + c] - (float)((const __bf16*)x)[dn*3 + c];
                s_rel[tid*3 + c] = r;
                d2 += r*r;
            }
            s_dist[tid] = d2;
        }
        #pragma unroll
        for (int r = 0; r < 2; ++r) {
            const int idx = tid + r*512;
            const int m = idx >> 5, c = idx & 31;
            const int e = ebase + m;
            const int node = (c < 16) ? ei[e] : ei[Ee + e];
            *(bf8_t*)&s_in[m*264 + c*8] = hload8(h, (size_t)node*H + (c & 15)*8, f32);
        }
        __syncthreads();

        {
            f4_t a0 = {0.f,0.f,0.f,0.f}, a1 = {0.f,0.f,0.f,0.f};
            const int abase = (mg*16 + l15)*264 + quad*8;
            #pragma unroll
            for (int kc = 0; kc < 8; ++kc) {
                const bf8_t a = *(const bf8_t*)&s_in[abase + kc*32];
                a0 = MFMA16(a, bW1[kc][0], a0);
                a1 = MFMA16(a, bW1[kc][1], a1);
            }
            #pragma unroll
            for (int i = 0; i < 4; ++i) {
                const int m = mg*16 + quad*4 + i;
                const float d2 = s_dist[m];
                s_m1[m*136 + ng*32 + l15]      = (__bf16)silu_f(a0[i] + d2*w1dv[0] + be1v[0]);
                s_m1[m*136 + ng*32 + 16 + l15] = (__bf16)silu_f(a1[i] + d2*w1dv[1] + be1v[1]);
            }
        }
        __syncthreads();

        {
            f4_t a0 = {0.f,0.f,0.f,0.f}, a1 = {0.f,0.f,0.f,0.f};
            const int abase = (mg*16 + l15)*136 + quad*8;
            #pragma unroll
            for (int kc = 0; kc < 4; ++kc) {
                const bf8_t a = *(const bf8_t*)&s_m1[abase + kc*32];
                a0 = MFMA16(a, bW2[kc][0], a0);
                a1 = MFMA16(a, bW2[kc][1], a1);
            }
            #pragma unroll
            for (int i = 0; i < 4; ++i) {
                const int m = mg*16 + quad*4 + i;
                const float v0 = silu_f(a0[i] + be2v[0]);
                const float v1 = silu_f(a1[i] + be2v[1]);
                s_m2[m*136 + ng*32 + l15]      = (__bf16)v0;
                s_m2[m*136 + ng*32 + 16 + l15] = (__bf16)v1;
                const size_t db = (size_t)s_dstv[m]*H + ng*32 + l15;
                atomicAdd(&msg_agg[db],      v0);
                atomicAdd(&msg_agg[db + 16], v1);
            }
        }
        __syncthreads();

        {
            f4_t a0 = {0.f,0.f,0.f,0.f}, a1 = {0.f,0.f,0.f,0.f};
            const int abase = (mg*16 + l15)*136 + quad*8;
            #pragma unroll
            for (int kc = 0; kc < 4; ++kc) {
                const bf8_t a = *(const bf8_t*)&s_m2[abase + kc*32];
                a0 = MFMA16(a, bWc[kc][0], a0);
                a1 = MFMA16(a, bWc[kc][1], a1);
            }
            float p[4];
            #pragma unroll
            for (int i = 0; i < 4; ++i) {
                const float v0 = silu_f(a0[i] + bc1v[0]);
                const float v1 = silu_f(a1[i] + bc1v[1]);
                p[i] = v0*wc2v[0] + v1*wc2v[1];
            }
            #pragma unroll
            for (int off = 1; off < 16; off <<= 1) {
                #pragma unroll
                for (int i = 0; i < 4; ++i) p[i] += __shfl_xor(p[i], off, 64);
            }
            if (l15 == 0) {
                #pragma unroll
                for (int i = 0; i < 4; ++i)
                    s_cw[(mg*16 + quad*4 + i)*4 + ng] = p[i];
            }
        }
        __syncthreads();

        if (tid < 96) {
            const int m = tid / 3, c = tid - m*3;
            const float cw = s_cw[m*4 + 0] + s_cw[m*4 + 1] + s_cw[m*4 + 2] + s_cw[m*4 + 3];
            atomicAdd(&coord_agg[(size_t)s_dstv[m]*3 + c], s_rel[m*3 + c]*cw);
        }
    }
}

__global__ void egnn_x_kernel(const void* __restrict__ x, const float* __restrict__ coord_agg,
                              const int* __restrict__ flags, void* __restrict__ out,
                              size_t obase, int total)
{
    const bool f32 = flags[0] != 0;
    const int i = blockIdx.x*blockDim.x + threadIdx.x;
    if (i >= total) return;
    const float xv = f32 ? ((const float*)x)[i] : (float)((const __bf16*)x)[i];
    const float o = xv + coord_agg[i];
    if (f32) ((float*)out)[obase + i] = o;
    else     ((__bf16*)out)[obase + i] = (__bf16)o;
}

static inline size_t align256(size_t v) { return (v + 255) & ~(size_t)255; }

extern "C" void kernel_launch(void* const* d_in, const int* in_sizes, int n_in,
                              void* d_out, int out_size, void* d_ws, size_t ws_size,
                              hipStream_t stream)
{
    const void* h   = d_in[0];
    const void* x   = d_in[1];
    const void* ei0 = d_in[2];
    const void* We1 = d_in[3];
    const void* be1 = d_in[4];
    const void* We2 = d_in[5];
    const void* be2 = d_in[6];
    const void* Wc1 = d_in[7];
    const void* bc1 = d_in[8];
    const void* Wc2 = d_in[9];
    const void* Wn1 = d_in[10];
    const void* bn1 = d_in[11];
    const void* Wn2 = d_in[12];
    const void* bn2 = d_in[13];

    const int Nn = in_sizes[0] / H;   // 50000
    const int Ee = in_sizes[2] / 2;   // 640000

    char* ws = (char*)d_ws;
    size_t o = 0;
    // zero-init region: cnt | msg | coord (one memset)
    size_t o_cnt   = o; o = align256(o + (size_t)Nn*4);
    size_t o_msg   = o; o = align256(o + (size_t)Nn*H*4);      // msg_agg f32
    size_t o_coord = o; o = align256(o + (size_t)Nn*3*4);      // coord_agg f32
    const size_t zero_end = o;
    size_t o_srcs  = o; o = align256(o + (size_t)Ee*4);
    size_t o_dsts  = o; o = align256(o + (size_t)Ee*4);
    size_t o_rel   = o; o = align256(o + (size_t)Ee*16);       // rel4 (xyz, d2)
    size_t o_pb    = o; o = align256(o + (size_t)Nn*256*2);    // PB bf16 [N,256]
    size_t o_off   = o; o = align256(o + (size_t)(Nn+1)*4);
    size_t o_cur   = o; o = align256(o + (size_t)Nn*4);
    size_t o_bsum  = o; o = align256(o + 512*4);
    size_t o_base  = o; o = align256(o + 512*4);
    size_t o_flags = o; o = align256(o + 64);
    const size_t need_csr = o;

    const int nCh = (Nn + 1 + 511) / 512;

    if (ws_size >= need_csr) {
        int*    cnt     = (int*)   (ws + o_cnt);
        float*  msg     = (float*) (ws + o_msg);
        float*  coord   = (float*) (ws + o_coord);
        int*    srcs    = (int*)   (ws + o_srcs);
        int*    dsts    = (int*)   (ws + o_dsts);
        float4* rel4    = (float4*)(ws + o_rel);
        __bf16* PB      = (__bf16*)(ws + o_pb);
        int*    off     = (int*)   (ws + o_off);
        int*    cursor  = (int*)   (ws + o_cur);
        int*    bsum    = (int*)   (ws + o_bsum);
        int*    base    = (int*)   (ws + o_base);
        int*    flags   = (int*)   (ws + o_flags);

        detect_kernel<<<1, 256, 0, stream>>>((const unsigned short*)h, (const int*)ei0, flags);
        hipMemsetAsync(ws + o_cnt, 0, zero_end - o_cnt, stream);
        histd_kernel<<<(Ee + 511)/512, 512, 0, stream>>>(ei0, cnt, flags, Ee);
        scanA_kernel<<<nCh, 512, 0, stream>>>(cnt, bsum, Nn);
        scanB_kernel<<<1, 64, 0, stream>>>(bsum, base, nCh);
        scanC_kernel<<<nCh, 512, 0, stream>>>(cnt, base, off, cursor, Nn);
        scatgeo_kernel<<<(Ee + 511)/512, 512, 0, stream>>>(ei0, cursor, srcs, dsts,
                                                           rel4, x, flags, Ee);
        proj_kernel<<<512, 512, 0, stream>>>(h, We1, be1, flags, PB, Nn);

        // grid 512: ~20 tiles/block, 2 blocks/CU (R5-proven best config)
        egnn_edge_pipe_kernel<<<512, 512, 0, stream>>>(PB, srcs, dsts, rel4,
                                                       We1, We2, be2, Wc1, bc1, Wc2,
                                                       flags, msg, coord, Ee);

        egnn_node_kernel<<<1024, 512, 0, stream>>>(h, msg, Wn1, bn1, Wn2, bn2,
                                                   flags, d_out, x, coord,
                                                   (size_t)Nn*H, 1, Nn);
    } else {
        // fallback: proven R2 atomic path
        float* msg_agg   = (float*)ws;
        float* coord_agg = (float*)(ws + (size_t)Nn*H*4);
        int*   ei        = (int*)  (ws + (size_t)Nn*H*4 + (size_t)Nn*3*4);
        int*   flags     = (int*)  (ws + (size_t)Nn*H*4 + (size_t)Nn*3*4 + (size_t)2*Ee*4);

        detect_kernel<<<1, 256, 0, stream>>>((const unsigned short*)h, (const int*)ei0, flags);
        cvt_ei_kernel<<<(2*Ee + 255)/256, 256, 0, stream>>>(ei0, ei, 2*Ee, flags);
        hipMemsetAsync(msg_agg,   0, (size_t)Nn*H*4, stream);
        hipMemsetAsync(coord_agg, 0, (size_t)Nn*3*4, stream);
        egnn_edge_kernel<<<1024, 512, 0, stream>>>(h, x, ei, We1, be1, We2, be2,
                                                   Wc1, bc1, Wc2, flags,
                                                   msg_agg, coord_agg, Nn, Ee);
        egnn_node_kernel<<<512, 512, 0, stream>>>(h, msg_agg, Wn1, bn1, Wn2, bn2,
                                                  flags, d_out, x, coord_agg,
                                                  (size_t)Nn*H, 0, Nn);
        egnn_x_kernel<<<(Nn*3 + 255)/256, 256, 0, stream>>>(x, coord_agg, flags, d_out,
                                                            (size_t)Nn*H, Nn*3);
    }
}